// Round 18
// baseline (189.662 us; speedup 1.0000x reference)
//
#include <hip/hip_runtime.h>
#include <hip/hip_bf16.h>
#include <math.h>

// BatchTreeEncoder: BS=32, A=4, D=6, H=E=256, V=50000
// Round 18: DOUBLE CO-RESIDENCY on the wall kernel. levelAB -> 512 blocks of
// (64 L6 rows + 16 L5 rows); LDS 116KB -> ~58KB -> 2 blocks/CU
// (launch_bounds(512,4), cap 128 >= measured 104). L6 = 2 passes (jc), same
// per-pass register shape as r14 (spill-free). L5 = level16 (r15/16/17-
// verified) extended with a global-compact-write mode (outMode 3).
// levelB (L4) + tailF2 (L3..L0) r17-verbatim.
// Dispatches: prep, levelAB(512), levelB(128), tailF2(32).

typedef unsigned short u16;
typedef unsigned int u32;
typedef __attribute__((ext_vector_type(8))) short s8;
typedef __attribute__((ext_vector_type(4))) float f4;
#define MFMA16(a, b, c) __builtin_amdgcn_mfma_f32_16x16x32_bf16(a, b, c, 0, 0, 0)

__device__ __forceinline__ u16 f2bf(float f) {
  u32 x = __float_as_uint(f);
  return (u16)((x + 0x7fffu + ((x >> 16) & 1u)) >> 16);
}
__device__ __forceinline__ float bf2f(u16 u) { return __uint_as_float(((u32)u) << 16); }
__device__ __forceinline__ float sigmoidf_(float x) {
  return __builtin_amdgcn_rcpf(1.f + __builtin_amdgcn_exp2f(-1.4426950408889634f * x));
}
__device__ __forceinline__ float tanhf_(float x) {
  x = fminf(fmaxf(x, -15.f), 15.f);
  float t = __builtin_amdgcn_exp2f(-2.8853900817779268f * x);
  return 1.f - 2.f * t * __builtin_amdgcn_rcpf(1.f + t);
}
__device__ __forceinline__ void gload_lds16(const void* g, void* l) {
  typedef const __attribute__((address_space(1))) unsigned int* gp_t;
  typedef __attribute__((address_space(3))) unsigned int* lp_t;
  __builtin_amdgcn_global_load_lds((gp_t)g, (lp_t)l, 16, 0, 0);
}
__device__ __forceinline__ void stage_row(const float* __restrict__ emb, int tok,
                                          u16* aX, int r, int lane) {
  float4 v = ((const float4*)(emb + (size_t)tok * 256))[lane];
  uint2 val = {(u32)f2bf(v.x) | ((u32)f2bf(v.y) << 16),
               (u32)f2bf(v.z) | ((u32)f2bf(v.w) << 16)};
  *(uint2*)&aX[r * 256 + ((((lane >> 1)) ^ (r & 7)) << 3) + (lane & 1) * 4] = val;
}

// ---- prep: weight pack (0..319), u0 + out-zero (320) ----
__global__ void prep_pack(const float* __restrict__ wih, const float* __restrict__ whh,
                          const float* __restrict__ sw, const float* __restrict__ sb,
                          const float* __restrict__ cw,
                          u16* __restrict__ wihP, u16* __restrict__ whhPh,
                          u16* __restrict__ whhPl, u16* __restrict__ swPh,
                          float* __restrict__ u0p, int* __restrict__ outI) {
  int b = blockIdx.x, t = threadIdx.x;
  if (b == 320) {
    #pragma unroll
    for (int k = 0; k < 32; ++k) outI[k * 256 + t] = 0;
    if (t < 64) {
      float s = 0.f;
      #pragma unroll
      for (int q = 0; q < 4; ++q) { int k = t + 64 * q; s += tanhf(sb[k]) * cw[k]; }
      #pragma unroll
      for (int off = 32; off >= 1; off >>= 1) s += __shfl_xor(s, off);
      if (t == 0) u0p[0] = tanhf(s);
    }
    return;
  }
  int g = b * 256 + t;
  const float* src;
  u16* dst;
  int idx, NF, lomode, trans;
  if (g < 24576)      { idx = g;         src = wih; dst = wihP;  NF = 48; lomode = 0; trans = 1; }
  else if (g < 49152) { idx = g - 24576; src = whh; dst = whhPh; NF = 48; lomode = 0; trans = 1; }
  else if (g < 73728) { idx = g - 49152; src = whh; dst = whhPl; NF = 48; lomode = 1; trans = 1; }
  else                { idx = g - 73728; src = sw;  dst = swPh;  NF = 16; lomode = 0; trans = 0; }
  int lane = idx & 63;
  int t2 = idx >> 6;
  int nf = t2 % NF, kb = t2 / NF;
  int n = nf * 16 + (lane & 15);
  int k0 = kb * 32 + (lane >> 4) * 8;
  float v[8];
  if (trans) {
    const float4* p = (const float4*)(src + (size_t)n * 256 + k0);
    float4 a = p[0], b2 = p[1];
    v[0] = a.x; v[1] = a.y; v[2] = a.z; v[3] = a.w;
    v[4] = b2.x; v[5] = b2.y; v[6] = b2.z; v[7] = b2.w;
  } else {
    #pragma unroll
    for (int j = 0; j < 8; ++j) v[j] = src[(size_t)(k0 + j) * 256 + n];
  }
  u16 o[8];
  #pragma unroll
  for (int j = 0; j < 8; ++j) {
    u16 hi = f2bf(v[j]);
    o[j] = lomode ? f2bf(v[j] - bf2f(hi)) : hi;
  }
  u32* d = (u32*)(dst + (size_t)idx * 8);
  #pragma unroll
  for (int j = 0; j < 4; ++j) d[j] = (u32)o[2 * j] | ((u32)o[2 * j + 1] << 16);
}

// ---- level16: one 16-row-padded GRU level. outMode: 0 none, 1 LDS compact,
// 2 LDS full, 3 GLOBAL compact (row gBase+asub). mode: 0 single-batch cm,
// 2 per-row atomic. ----
__device__ __forceinline__ void level16(
    const u16* __restrict__ aXp, const u16* __restrict__ aHh,
    const u16* __restrict__ aHl,
    const u16* __restrict__ wihP, const u16* __restrict__ whhPh,
    const u16* __restrict__ whhPl, const u16* __restrict__ swPh,
    const float* __restrict__ bih, const float* __restrict__ bhh,
    const float* __restrict__ sb, const float* __restrict__ cw, float u0v,
    float logSm1, int nvalid, u16* outHh, u16* outHl, int outMode,
    u16* __restrict__ gHi, u16* __restrict__ gLo, int gBase,
    int* __restrict__ outI, int mode, int batchBase,
    float (*pm)[32], float* scl, int t) {
  const int lane = t & 63, w = t >> 6;
  const int asub = lane >> 4, l15 = lane & 15;
  f4 sa0 = (f4){0.f, 0.f, 0.f, 0.f}, sa1 = (f4){0.f, 0.f, 0.f, 0.f};
  #pragma unroll
  for (int kb = 0; kb < 8; ++kb) {
    s8 b0 = *(const s8*)&swPh[((size_t)(kb * 16 + 2 * w) * 64 + lane) * 8];
    s8 b1 = *(const s8*)&swPh[((size_t)(kb * 16 + 2 * w + 1) * 64 + lane) * 8];
    int ab = ((kb * 4 + asub) * 16 + l15) * 8;
    s8 ahh = *(const s8*)&aHh[ab];
    s8 ahl = *(const s8*)&aHl[ab];
    sa0 = MFMA16(ahh, b0, sa0); sa0 = MFMA16(ahl, b0, sa0);
    sa1 = MFMA16(ahh, b1, sa1); sa1 = MFMA16(ahl, b1, sa1);
  }
  {
    float part[4] = {0.f, 0.f, 0.f, 0.f};
    #pragma unroll
    for (int jc = 0; jc < 2; ++jc) {
      int k = 16 * (2 * w + jc) + l15;
      float sbk = sb[k], cwk = cw[k];
      #pragma unroll
      for (int j = 0; j < 4; ++j)
        part[j] += tanhf_((jc ? sa1[j] : sa0[j]) + sbk) * cwk;
    }
    #pragma unroll
    for (int j = 0; j < 4; ++j) {
      part[j] += __shfl_xor(part[j], 1);
      part[j] += __shfl_xor(part[j], 2);
      part[j] += __shfl_xor(part[j], 4);
      part[j] += __shfl_xor(part[j], 8);
    }
    if (l15 == 0) {
      #pragma unroll
      for (int j = 0; j < 4; ++j) pm[w][4 * asub + j] = part[j];
    }
    __syncthreads();
    if (t < 16) {
      float v = 0.f;
      #pragma unroll
      for (int q = 0; q < 8; ++q) v += pm[q][t];
      scl[t] = sigmoidf_(tanhf_(v) - u0v - logSm1);
    }
    __syncthreads();
  }
  #pragma unroll 1
  for (int p = 0; p < 2; ++p) {
    const int cf = w + 8 * p;
    f4 gi5[3], gh5[3];
    #pragma unroll
    for (int g = 0; g < 3; ++g) {
      gi5[g] = (f4){0.f, 0.f, 0.f, 0.f};
      gh5[g] = (f4){0.f, 0.f, 0.f, 0.f};
    }
    #pragma unroll
    for (int kb = 0; kb < 8; ++kb) {
      s8 bwi[3], bwh[3], bwl[3];
      #pragma unroll
      for (int g = 0; g < 3; ++g) {
        size_t bo = ((size_t)(kb * 48 + 16 * g + cf) * 64 + lane) * 8;
        bwi[g] = *(const s8*)&wihP[bo];
        bwh[g] = *(const s8*)&whhPh[bo];
        bwl[g] = *(const s8*)&whhPl[bo];
      }
      int axb = l15 * 256 + (((kb * 4 + asub) ^ (l15 & 7)) << 3);
      s8 axh = *(const s8*)&aXp[axb];
      int ab = ((kb * 4 + asub) * 16 + l15) * 8;
      s8 ahh = *(const s8*)&aHh[ab];
      s8 ahl = *(const s8*)&aHl[ab];
      #pragma unroll
      for (int g = 0; g < 3; ++g) {
        gi5[g] = MFMA16(axh, bwi[g], gi5[g]);
        gh5[g] = MFMA16(ahh, bwh[g], gh5[g]);
        gh5[g] = MFMA16(ahl, bwh[g], gh5[g]);
        gh5[g] = MFMA16(ahh, bwl[g], gh5[g]);
      }
    }
    const int col = 16 * cf + l15;
    const float bi0 = bih[col], bi1 = bih[256 + col], bi2 = bih[512 + col];
    const float bh0 = bhh[col], bh1 = bhh[256 + col], bh2 = bhh[512 + col];
    float cm = -1e30f;
    #pragma unroll
    for (int j = 0; j < 4; ++j) {
      const int row = 4 * asub + j;
      const int valid = row < nvalid;
      float sc = scl[row];
      float ir = gi5[0][j] + bi0;
      float iz = gi5[1][j] + bi1;
      float inn = gi5[2][j] + bi2;
      float g0 = bh0 + sc * gh5[0][j];
      float g1 = bh1 + sc * gh5[1][j];
      float g2 = bh2 + sc * gh5[2][j];
      int hix = ((col >> 3) * 16 + row) * 8 + (col & 7);
      float hp = sc * (bf2f(aHh[hix]) + bf2f(aHl[hix]));
      float r = sigmoidf_(ir + g0);
      float z = sigmoidf_(iz + g1);
      float n = tanhf_(inn + r * g2);
      float h = (1.f - z) * n + z * hp;
      u16 hi = f2bf(h);
      u16 lo = f2bf(h - bf2f(hi));
      if (outMode == 1 && j == 3 && valid) {
        int ho = ((col >> 3) * 16 + asub) * 8 + (col & 7);
        outHh[ho] = hi; outHl[ho] = lo;
      } else if (outMode == 2 && valid) {
        outHh[hix] = hi; outHl[hix] = lo;
      } else if (outMode == 3 && j == 3 && valid) {
        gHi[(size_t)(gBase + asub) * 256 + col] = hi;
        gLo[(size_t)(gBase + asub) * 256 + col] = lo;
      }
      if (mode == 2) {
        if (valid)
          atomicMax(outI + (size_t)(batchBase + row) * 256 + col, __float_as_int(h));
      } else if (valid) {
        cm = fmaxf(cm, h);
      }
    }
    if (mode == 0) {
      cm = fmaxf(cm, __shfl_xor(cm, 16));
      cm = fmaxf(cm, __shfl_xor(cm, 32));
      if (asub == 0)
        atomicMax(outI + (size_t)batchBase * 256 + col, __float_as_int(cm));
    }
  }
}

// ---- levelAB: fused L6(64r) + L5(16r). 512 blocks, 2 blocks/CU. ----
__global__ __launch_bounds__(512, 4)
void levelAB_kernel(const int* __restrict__ t6, const int* __restrict__ t5,
                    const float* __restrict__ emb,
                    const u16* __restrict__ wihP, const u16* __restrict__ whhPh,
                    const u16* __restrict__ whhPl, const u16* __restrict__ swPh,
                    const float* __restrict__ bih, const float* __restrict__ bhh,
                    const float* __restrict__ sb, const float* __restrict__ cw,
                    const float* __restrict__ u0p,
                    u16* __restrict__ Hs5Hi, u16* __restrict__ Hs5Lo,
                    int* __restrict__ outI) {
  __shared__ u16 aX6[16384];   // [64][256], chunk-swizzled
  __shared__ u16 aX5[4096];    // [16][256]
  __shared__ u16 aHh[4096], aHl[4096];  // h6 compact, 16-row transposed
  __shared__ float pm[8][32];
  __shared__ float scl[32];

  const int t = threadIdx.x;
  const int rb = blockIdx.x;   // 0..511
  const int lane = t & 63, w = t >> 6;
  const int asub = lane >> 4, l15 = lane & 15;
  const float LN3 = 1.0986122886681098f;
  const int batch = rb >> 4;

  {
    #pragma unroll
    for (int rr = 0; rr < 8; ++rr) {
      int r = 8 * w + rr;
      stage_row(emb, t6[4 * (64 * rb + r) + 3], aX6, r, lane);
    }
    #pragma unroll
    for (int rr = 0; rr < 2; ++rr) {
      int r = 2 * w + rr;
      stage_row(emb, t5[4 * (16 * rb + r) + 3], aX5, r, lane);
    }
  }
  __syncthreads();

  // ---- L6: 2 passes over jc (same per-pass shape as r14) ----
  #pragma unroll 1
  for (int jc = 0; jc < 2; ++jc) {
    const int cfx = 2 * w + jc;
    f4 gi[3][4];
    #pragma unroll
    for (int g = 0; g < 3; ++g)
      #pragma unroll
      for (int mf = 0; mf < 4; ++mf) gi[g][mf] = (f4){0.f, 0.f, 0.f, 0.f};
    s8 bw[2][3];
    auto LB = [&](int kb, int pb) {
      #pragma unroll
      for (int g = 0; g < 3; ++g)
        bw[pb][g] = *(const s8*)&wihP[((size_t)(kb * 48 + 16 * g + cfx) * 64 + lane) * 8];
    };
    LB(0, 0);
    #pragma unroll
    for (int kb = 0; kb < 8; ++kb) {
      const int pb = kb & 1;
      if (kb < 7) LB(kb + 1, pb ^ 1);
      s8 axh[4];
      #pragma unroll
      for (int mf = 0; mf < 4; ++mf) {
        int ab = (16 * mf + l15) * 256 + (((kb * 4 + asub) ^ (l15 & 7)) << 3);
        axh[mf] = *(const s8*)&aX6[ab];
      }
      #pragma unroll
      for (int g = 0; g < 3; ++g)
        #pragma unroll
        for (int mf = 0; mf < 4; ++mf)
          gi[g][mf] = MFMA16(axh[mf], bw[pb][g], gi[g][mf]);
    }
    const int col = 16 * cfx + l15;
    const float bi0 = bih[col], bi1 = bih[256 + col], bi2 = bih[512 + col];
    const float bh0 = bhh[col], bh1 = bhh[256 + col], bh2 = bhh[512 + col];
    float cm = -1e30f;
    #pragma unroll
    for (int mf = 0; mf < 4; ++mf) {
      #pragma unroll
      for (int j = 0; j < 4; ++j) {
        float r = sigmoidf_(gi[0][mf][j] + bi0 + bh0);
        float z = sigmoidf_(gi[1][mf][j] + bi1 + bh1);
        float n = tanhf_(gi[2][mf][j] + bi2 + r * bh2);
        float h = (1.f - z) * n;
        if (j == 3) {
          int ci = 4 * mf + asub;   // compact row 0..15
          u16 hi = f2bf(h);
          u16 lo = f2bf(h - bf2f(hi));
          int hidx = ((col >> 3) * 16 + ci) * 8 + (col & 7);
          aHh[hidx] = hi;
          aHl[hidx] = lo;
        }
        cm = fmaxf(cm, h);
      }
    }
    cm = fmaxf(cm, __shfl_xor(cm, 16));
    cm = fmaxf(cm, __shfl_xor(cm, 32));
    if (asub == 0)
      atomicMax(outI + (size_t)batch * 256 + col, __float_as_int(cm));
  }
  __syncthreads();

  // ---- L5: level16 with global compact write (rows 4rb..4rb+3 of Hs5) ----
  level16(aX5, aHh, aHl, wihP, whhPh, whhPl, swPh, bih, bhh, sb, cw, u0p[0],
          LN3, 16, nullptr, nullptr, 3, Hs5Hi, Hs5Lo, 4 * rb,
          outI, 0, batch, pm, scl, t);
}

// ---- levelB: L4. col-split x2 (r14/r17 verbatim) ----
__global__ __launch_bounds__(512, 2)
void levelB_kernel(const int* __restrict__ tokens, const float* __restrict__ emb,
                   const u16* __restrict__ wihP, const u16* __restrict__ whhPh,
                   const u16* __restrict__ whhPl, const u16* __restrict__ swPh,
                   const float* __restrict__ bih, const float* __restrict__ bhh,
                   const float* __restrict__ sb, const float* __restrict__ cw,
                   const float* __restrict__ u0p,
                   const u16* __restrict__ HpHi, const u16* __restrict__ HpLo,
                   u16* __restrict__ HoutHi, u16* __restrict__ HoutLo,
                   int* __restrict__ outI, float logSm1, int bshift) {
  __shared__ u16 aX[8192];
  __shared__ u16 aH[2][8192];
  __shared__ float pm[8][32];
  __shared__ float scl[32];

  const int t = threadIdx.x;
  const int rb = blockIdx.x >> 1, cb = blockIdx.x & 1;
  const int i0 = rb * 32;
  const int lane = t & 63, w = t >> 6;

  {
    int row = lane & 31;
    const u16* sh = HpHi + ((size_t)(i0 + row) << 8);
    const u16* sl = HpLo + ((size_t)(i0 + row) << 8);
    #pragma unroll
    for (int c = 0; c < 2; ++c) {
      int cg = w * 4 + c * 2 + (lane >> 5);
      int lb = w * 1024 + c * 512;
      gload_lds16(sh + (cg << 3), &aH[0][lb]);
      gload_lds16(sl + (cg << 3), &aH[1][lb]);
    }
  }
  {
    #pragma unroll
    for (int rr = 0; rr < 4; ++rr) {
      int r = 4 * w + rr;
      int tok = tokens[4 * (i0 + r) + 3];
      stage_row(emb, tok, aX, r, lane);
    }
  }
  __syncthreads();

  const int asub = lane >> 4, l15 = lane & 15;
  const int cfg = 8 * cb + w;

  f4 gi[3][2], gh[3][2], sa[2][2];
  #pragma unroll
  for (int g = 0; g < 3; ++g)
    #pragma unroll
    for (int mf = 0; mf < 2; ++mf) {
      gi[g][mf] = (f4){0.f, 0.f, 0.f, 0.f};
      gh[g][mf] = (f4){0.f, 0.f, 0.f, 0.f};
    }
  #pragma unroll
  for (int jc = 0; jc < 2; ++jc)
    #pragma unroll
    for (int mf = 0; mf < 2; ++mf) sa[jc][mf] = (f4){0.f, 0.f, 0.f, 0.f};

  #pragma unroll
  for (int kb = 0; kb < 8; ++kb) {
    s8 bwi[3], bwh[3], bwl[3], bsw[2];
    #pragma unroll
    for (int g = 0; g < 3; ++g) {
      size_t bo = ((size_t)(kb * 48 + 16 * g + cfg) * 64 + lane) * 8;
      bwi[g] = *(const s8*)&wihP[bo];
      bwh[g] = *(const s8*)&whhPh[bo];
      bwl[g] = *(const s8*)&whhPl[bo];
    }
    #pragma unroll
    for (int jc = 0; jc < 2; ++jc) {
      size_t so = ((size_t)(kb * 16 + 2 * w + jc) * 64 + lane) * 8;
      bsw[jc] = *(const s8*)&swPh[so];
    }
    s8 axh[2], ahh[2], ahl[2];
    #pragma unroll
    for (int mf = 0; mf < 2; ++mf) {
      int axb = (16 * mf + l15) * 256 + (((kb * 4 + asub) ^ (l15 & 7)) << 3);
      axh[mf] = *(const s8*)&aX[axb];
      int abase = ((kb * 4 + asub) * 32 + 16 * mf + l15) * 8;
      ahh[mf] = *(const s8*)&aH[0][abase];
      ahl[mf] = *(const s8*)&aH[1][abase];
    }
    #pragma unroll
    for (int g = 0; g < 3; ++g) {
      gi[g][0] = MFMA16(axh[0], bwi[g], gi[g][0]);
      gi[g][1] = MFMA16(axh[1], bwi[g], gi[g][1]);
      gh[g][0] = MFMA16(ahh[0], bwh[g], gh[g][0]);
      gh[g][1] = MFMA16(ahh[1], bwh[g], gh[g][1]);
      gh[g][0] = MFMA16(ahl[0], bwh[g], gh[g][0]);
      gh[g][1] = MFMA16(ahl[1], bwh[g], gh[g][1]);
      gh[g][0] = MFMA16(ahh[0], bwl[g], gh[g][0]);
      gh[g][1] = MFMA16(ahh[1], bwl[g], gh[g][1]);
    }
    #pragma unroll
    for (int jc = 0; jc < 2; ++jc) {
      sa[jc][0] = MFMA16(ahh[0], bsw[jc], sa[jc][0]);
      sa[jc][1] = MFMA16(ahh[1], bsw[jc], sa[jc][1]);
      sa[jc][0] = MFMA16(ahl[0], bsw[jc], sa[jc][0]);
      sa[jc][1] = MFMA16(ahl[1], bsw[jc], sa[jc][1]);
    }
  }

  {
    float part[2][4] = {{0.f, 0.f, 0.f, 0.f}, {0.f, 0.f, 0.f, 0.f}};
    #pragma unroll
    for (int jc = 0; jc < 2; ++jc) {
      int k = 16 * (2 * w + jc) + l15;
      float sbk = sb[k], cwk = cw[k];
      #pragma unroll
      for (int mf = 0; mf < 2; ++mf)
        #pragma unroll
        for (int j = 0; j < 4; ++j) part[mf][j] += tanhf_(sa[jc][mf][j] + sbk) * cwk;
    }
    #pragma unroll
    for (int mf = 0; mf < 2; ++mf)
      #pragma unroll
      for (int j = 0; j < 4; ++j) {
        part[mf][j] += __shfl_xor(part[mf][j], 1);
        part[mf][j] += __shfl_xor(part[mf][j], 2);
        part[mf][j] += __shfl_xor(part[mf][j], 4);
        part[mf][j] += __shfl_xor(part[mf][j], 8);
      }
    if (l15 == 0) {
      #pragma unroll
      for (int mf = 0; mf < 2; ++mf)
        #pragma unroll
        for (int j = 0; j < 4; ++j) pm[w][16 * mf + 4 * asub + j] = part[mf][j];
    }
    __syncthreads();
    if (t < 32) {
      float v = 0.f;
      #pragma unroll
      for (int q = 0; q < 8; ++q) v += pm[q][t];
      scl[t] = sigmoidf_(tanhf_(v) - u0p[0] - logSm1);
    }
    __syncthreads();
  }

  {
    const int col = 16 * cfg + l15;
    const float bi0 = bih[col], bi1 = bih[256 + col], bi2 = bih[512 + col];
    const float bh0 = bhh[col], bh1 = bhh[256 + col], bh2 = bhh[512 + col];
    float cmax = -1e30f;
    #pragma unroll
    for (int mf = 0; mf < 2; ++mf) {
      const int r0 = 16 * mf + 4 * asub;
      #pragma unroll
      for (int j = 0; j < 4; ++j) {
        const int row = r0 + j;
        const int i = i0 + row;
        float sc = scl[row];
        float ir = gi[0][mf][j] + bi0;
        float iz = gi[1][mf][j] + bi1;
        float inn = gi[2][mf][j] + bi2;
        float g0 = bh0 + sc * gh[0][mf][j];
        float g1 = bh1 + sc * gh[1][mf][j];
        float g2 = bh2 + sc * gh[2][mf][j];
        int hidx = ((col >> 3) * 32 + row) * 8 + (col & 7);
        float hp = sc * (bf2f(aH[0][hidx]) + bf2f(aH[1][hidx]));
        float r = sigmoidf_(ir + g0);
        float z = sigmoidf_(iz + g1);
        float n = tanhf_(inn + r * g2);
        float h = (1.f - z) * n + z * hp;
        if ((i & 3) == 3) {
          u16 hi = f2bf(h);
          u16 lo = f2bf(h - bf2f(hi));
          HoutHi[(size_t)(i >> 2) * 256 + col] = hi;
          HoutLo[(size_t)(i >> 2) * 256 + col] = lo;
        }
        cmax = fmaxf(cmax, h);
      }
    }
    cmax = fmaxf(cmax, __shfl_xor(cmax, 16));
    cmax = fmaxf(cmax, __shfl_xor(cmax, 32));
    if (asub == 0)
      atomicMax(outI + (size_t)(i0 >> bshift) * 256 + col, __float_as_int(cmax));
  }
}

// ---- tailF2: L3(16r) -> L2(4r) -> L1(1r) -> L0(1r) per block, 32 blocks ----
__global__ __launch_bounds__(512, 2)
void tailF2_kernel(const int* __restrict__ t3, const int* __restrict__ t2,
                   const int* __restrict__ t1, const int* __restrict__ t0,
                   const float* __restrict__ emb,
                   const u16* __restrict__ wihP, const u16* __restrict__ whhPh,
                   const u16* __restrict__ whhPl, const u16* __restrict__ swPh,
                   const float* __restrict__ bih, const float* __restrict__ bhh,
                   const float* __restrict__ sb, const float* __restrict__ cw,
                   const float* __restrict__ u0p,
                   const u16* __restrict__ Hs4Hi, const u16* __restrict__ Hs4Lo,
                   int* __restrict__ outI) {
  __shared__ u16 aX3[4096], aH3h[4096], aH3l[4096];
  __shared__ u16 aX2[4096], aH2h[4096], aH2l[4096];
  __shared__ u16 aX1[4096], aH1h[4096], aH1l[4096];
  __shared__ u16 aX0[4096], aH0h[4096], aH0l[4096];
  __shared__ float pm[8][32];
  __shared__ float scl[32];

  const int t = threadIdx.x, b = blockIdx.x;
  const int lane = t & 63, w = t >> 6;
  const float LN3 = 1.0986122886681098f;
  const float LN31 = 3.4339872044851463f;
  const float u0v = u0p[0];

  {
    int row = t & 15, kg = t >> 4;
    uint4 vh = *(const uint4*)&Hs4Hi[(size_t)(16 * b + row) * 256 + kg * 8];
    uint4 vl = *(const uint4*)&Hs4Lo[(size_t)(16 * b + row) * 256 + kg * 8];
    *(uint4*)&aH3h[(kg * 16 + row) * 8] = vh;
    *(uint4*)&aH3l[(kg * 16 + row) * 8] = vl;
    stage_row(emb, t3[4 * (16 * b + w) + 3], aX3, w, lane);
    stage_row(emb, t3[4 * (16 * b + w + 8) + 3], aX3, w + 8, lane);
    if (w < 4) stage_row(emb, t2[4 * (4 * b + w) + 3], aX2, w, lane);
    if (w == 4) stage_row(emb, t1[4 * b + 3], aX1, 0, lane);
    if (w == 5) stage_row(emb, t0[b], aX0, 0, lane);
  }
  __syncthreads();

  level16(aX3, aH3h, aH3l, wihP, whhPh, whhPl, swPh, bih, bhh, sb, cw, u0v,
          LN3, 16, aH2h, aH2l, 1, nullptr, nullptr, 0, outI, 0, b, pm, scl, t);
  __syncthreads();
  level16(aX2, aH2h, aH2l, wihP, whhPh, whhPl, swPh, bih, bhh, sb, cw, u0v,
          LN3, 4, aH1h, aH1l, 1, nullptr, nullptr, 0, outI, 0, b, pm, scl, t);
  __syncthreads();
  level16(aX1, aH1h, aH1l, wihP, whhPh, whhPl, swPh, bih, bhh, sb, cw, u0v,
          LN3, 1, aH0h, aH0l, 2, nullptr, nullptr, 0, outI, 2, b, pm, scl, t);
  __syncthreads();
  level16(aX0, aH0h, aH0l, wihP, whhPh, whhPl, swPh, bih, bhh, sb, cw, u0v,
          LN31, 1, nullptr, nullptr, 0, nullptr, nullptr, 0, outI, 2, b, pm, scl, t);
}

extern "C" void kernel_launch(void* const* d_in, const int* in_sizes, int n_in,
                              void* d_out, int out_size, void* d_ws, size_t ws_size,
                              hipStream_t stream) {
  const int*   tokens = (const int*)d_in[0];
  const float* emb    = (const float*)d_in[1];
  const float* wih    = (const float*)d_in[2];
  const float* whh    = (const float*)d_in[3];
  const float* bih    = (const float*)d_in[4];
  const float* bhh    = (const float*)d_in[5];
  const float* sw     = (const float*)d_in[6];
  const float* sb     = (const float*)d_in[7];
  const float* cw     = (const float*)d_in[8];

  char* ws = (char*)d_ws;
  u16* wihP  = (u16*)(ws + 0);
  u16* whhPh = (u16*)(ws + 393216);
  u16* whhPl = (u16*)(ws + 786432);
  u16* swPh  = (u16*)(ws + 1179648);
  float* u0p = (float*)(ws + 1310720);
  u16* Hs5Hi = (u16*)(ws + 9961472);
  u16* Hs5Lo = (u16*)(ws + 11010048);
  u16* Hs4Hi = (u16*)(ws + 12058624);
  u16* Hs4Lo = (u16*)(ws + 12320768);

  int* outI = (int*)d_out;
  prep_pack<<<321, 256, 0, stream>>>(wih, whh, sw, sb, cw,
                                     wihP, whhPh, whhPl, swPh, u0p, outI);

  const float LN3 = 1.0986122886681098f;

  // L6 + L5 fused, 512 blocks (2 blocks/CU)
  levelAB_kernel<<<512, 512, 0, stream>>>(
      tokens + 43680, tokens + 10912, emb, wihP, whhPh, whhPl, swPh,
      bih, bhh, sb, cw, u0p, Hs5Hi, Hs5Lo, outI);
  // L4
  levelB_kernel<<<128, 512, 0, stream>>>(
      tokens + 2720, emb, wihP, whhPh, whhPl, swPh, bih, bhh, sb, cw, u0p,
      Hs5Hi, Hs5Lo, Hs4Hi, Hs4Lo, outI, LN3, 6);
  // L3 -> L2 -> L1 -> L0 fused
  tailF2_kernel<<<32, 512, 0, stream>>>(
      tokens + 672, tokens + 160, tokens + 32, tokens, emb,
      wihP, whhPh, whhPl, swPh, bih, bhh, sb, cw, u0p, Hs4Hi, Hs4Lo, outI);
}

// Round 19
// 127.687 us; speedup vs baseline: 1.4854x; 1.4854x over previous
//
#include <hip/hip_runtime.h>
#include <hip/hip_bf16.h>
#include <math.h>

// BatchTreeEncoder: BS=32, A=4, D=6, H=E=256, V=50000
// Round 19: r18 structure with the launch-bounds fix. r18's
// __launch_bounds__(512,4) made the allocator target the 64-VGPR tier ->
// 146MB spill. (512,2) restores the proven ~104-VGPR spill-free shape;
// occupancy is then resource-limited: LDS 58KB -> 2 blocks/CU (the
// co-residency r18 wanted). Everything else r18-identical:
//  - levelAB: 512 blocks of (64 L6 rows + 16 L5 rows); L6 = 2 passes (jc);
//    L5 = level16 with global compact write.
//  - levelB (L4) + tailF2 (L3..L0) r17-verbatim.
// Dispatches: prep, levelAB(512), levelB(128), tailF2(32).

typedef unsigned short u16;
typedef unsigned int u32;
typedef __attribute__((ext_vector_type(8))) short s8;
typedef __attribute__((ext_vector_type(4))) float f4;
#define MFMA16(a, b, c) __builtin_amdgcn_mfma_f32_16x16x32_bf16(a, b, c, 0, 0, 0)

__device__ __forceinline__ u16 f2bf(float f) {
  u32 x = __float_as_uint(f);
  return (u16)((x + 0x7fffu + ((x >> 16) & 1u)) >> 16);
}
__device__ __forceinline__ float bf2f(u16 u) { return __uint_as_float(((u32)u) << 16); }
__device__ __forceinline__ float sigmoidf_(float x) {
  return __builtin_amdgcn_rcpf(1.f + __builtin_amdgcn_exp2f(-1.4426950408889634f * x));
}
__device__ __forceinline__ float tanhf_(float x) {
  x = fminf(fmaxf(x, -15.f), 15.f);
  float t = __builtin_amdgcn_exp2f(-2.8853900817779268f * x);
  return 1.f - 2.f * t * __builtin_amdgcn_rcpf(1.f + t);
}
__device__ __forceinline__ void gload_lds16(const void* g, void* l) {
  typedef const __attribute__((address_space(1))) unsigned int* gp_t;
  typedef __attribute__((address_space(3))) unsigned int* lp_t;
  __builtin_amdgcn_global_load_lds((gp_t)g, (lp_t)l, 16, 0, 0);
}
__device__ __forceinline__ void stage_row(const float* __restrict__ emb, int tok,
                                          u16* aX, int r, int lane) {
  float4 v = ((const float4*)(emb + (size_t)tok * 256))[lane];
  uint2 val = {(u32)f2bf(v.x) | ((u32)f2bf(v.y) << 16),
               (u32)f2bf(v.z) | ((u32)f2bf(v.w) << 16)};
  *(uint2*)&aX[r * 256 + ((((lane >> 1)) ^ (r & 7)) << 3) + (lane & 1) * 4] = val;
}

// ---- prep: weight pack (0..319), u0 + out-zero (320) ----
__global__ void prep_pack(const float* __restrict__ wih, const float* __restrict__ whh,
                          const float* __restrict__ sw, const float* __restrict__ sb,
                          const float* __restrict__ cw,
                          u16* __restrict__ wihP, u16* __restrict__ whhPh,
                          u16* __restrict__ whhPl, u16* __restrict__ swPh,
                          float* __restrict__ u0p, int* __restrict__ outI) {
  int b = blockIdx.x, t = threadIdx.x;
  if (b == 320) {
    #pragma unroll
    for (int k = 0; k < 32; ++k) outI[k * 256 + t] = 0;
    if (t < 64) {
      float s = 0.f;
      #pragma unroll
      for (int q = 0; q < 4; ++q) { int k = t + 64 * q; s += tanhf(sb[k]) * cw[k]; }
      #pragma unroll
      for (int off = 32; off >= 1; off >>= 1) s += __shfl_xor(s, off);
      if (t == 0) u0p[0] = tanhf(s);
    }
    return;
  }
  int g = b * 256 + t;
  const float* src;
  u16* dst;
  int idx, NF, lomode, trans;
  if (g < 24576)      { idx = g;         src = wih; dst = wihP;  NF = 48; lomode = 0; trans = 1; }
  else if (g < 49152) { idx = g - 24576; src = whh; dst = whhPh; NF = 48; lomode = 0; trans = 1; }
  else if (g < 73728) { idx = g - 49152; src = whh; dst = whhPl; NF = 48; lomode = 1; trans = 1; }
  else                { idx = g - 73728; src = sw;  dst = swPh;  NF = 16; lomode = 0; trans = 0; }
  int lane = idx & 63;
  int t2 = idx >> 6;
  int nf = t2 % NF, kb = t2 / NF;
  int n = nf * 16 + (lane & 15);
  int k0 = kb * 32 + (lane >> 4) * 8;
  float v[8];
  if (trans) {
    const float4* p = (const float4*)(src + (size_t)n * 256 + k0);
    float4 a = p[0], b2 = p[1];
    v[0] = a.x; v[1] = a.y; v[2] = a.z; v[3] = a.w;
    v[4] = b2.x; v[5] = b2.y; v[6] = b2.z; v[7] = b2.w;
  } else {
    #pragma unroll
    for (int j = 0; j < 8; ++j) v[j] = src[(size_t)(k0 + j) * 256 + n];
  }
  u16 o[8];
  #pragma unroll
  for (int j = 0; j < 8; ++j) {
    u16 hi = f2bf(v[j]);
    o[j] = lomode ? f2bf(v[j] - bf2f(hi)) : hi;
  }
  u32* d = (u32*)(dst + (size_t)idx * 8);
  #pragma unroll
  for (int j = 0; j < 4; ++j) d[j] = (u32)o[2 * j] | ((u32)o[2 * j + 1] << 16);
}

// ---- level16: one 16-row-padded GRU level. outMode: 0 none, 1 LDS compact,
// 2 LDS full, 3 GLOBAL compact (row gBase+asub). mode: 0 single-batch cm,
// 2 per-row atomic. ----
__device__ __forceinline__ void level16(
    const u16* __restrict__ aXp, const u16* __restrict__ aHh,
    const u16* __restrict__ aHl,
    const u16* __restrict__ wihP, const u16* __restrict__ whhPh,
    const u16* __restrict__ whhPl, const u16* __restrict__ swPh,
    const float* __restrict__ bih, const float* __restrict__ bhh,
    const float* __restrict__ sb, const float* __restrict__ cw, float u0v,
    float logSm1, int nvalid, u16* outHh, u16* outHl, int outMode,
    u16* __restrict__ gHi, u16* __restrict__ gLo, int gBase,
    int* __restrict__ outI, int mode, int batchBase,
    float (*pm)[32], float* scl, int t) {
  const int lane = t & 63, w = t >> 6;
  const int asub = lane >> 4, l15 = lane & 15;
  f4 sa0 = (f4){0.f, 0.f, 0.f, 0.f}, sa1 = (f4){0.f, 0.f, 0.f, 0.f};
  #pragma unroll
  for (int kb = 0; kb < 8; ++kb) {
    s8 b0 = *(const s8*)&swPh[((size_t)(kb * 16 + 2 * w) * 64 + lane) * 8];
    s8 b1 = *(const s8*)&swPh[((size_t)(kb * 16 + 2 * w + 1) * 64 + lane) * 8];
    int ab = ((kb * 4 + asub) * 16 + l15) * 8;
    s8 ahh = *(const s8*)&aHh[ab];
    s8 ahl = *(const s8*)&aHl[ab];
    sa0 = MFMA16(ahh, b0, sa0); sa0 = MFMA16(ahl, b0, sa0);
    sa1 = MFMA16(ahh, b1, sa1); sa1 = MFMA16(ahl, b1, sa1);
  }
  {
    float part[4] = {0.f, 0.f, 0.f, 0.f};
    #pragma unroll
    for (int jc = 0; jc < 2; ++jc) {
      int k = 16 * (2 * w + jc) + l15;
      float sbk = sb[k], cwk = cw[k];
      #pragma unroll
      for (int j = 0; j < 4; ++j)
        part[j] += tanhf_((jc ? sa1[j] : sa0[j]) + sbk) * cwk;
    }
    #pragma unroll
    for (int j = 0; j < 4; ++j) {
      part[j] += __shfl_xor(part[j], 1);
      part[j] += __shfl_xor(part[j], 2);
      part[j] += __shfl_xor(part[j], 4);
      part[j] += __shfl_xor(part[j], 8);
    }
    if (l15 == 0) {
      #pragma unroll
      for (int j = 0; j < 4; ++j) pm[w][4 * asub + j] = part[j];
    }
    __syncthreads();
    if (t < 16) {
      float v = 0.f;
      #pragma unroll
      for (int q = 0; q < 8; ++q) v += pm[q][t];
      scl[t] = sigmoidf_(tanhf_(v) - u0v - logSm1);
    }
    __syncthreads();
  }
  #pragma unroll 1
  for (int p = 0; p < 2; ++p) {
    const int cf = w + 8 * p;
    f4 gi5[3], gh5[3];
    #pragma unroll
    for (int g = 0; g < 3; ++g) {
      gi5[g] = (f4){0.f, 0.f, 0.f, 0.f};
      gh5[g] = (f4){0.f, 0.f, 0.f, 0.f};
    }
    #pragma unroll
    for (int kb = 0; kb < 8; ++kb) {
      s8 bwi[3], bwh[3], bwl[3];
      #pragma unroll
      for (int g = 0; g < 3; ++g) {
        size_t bo = ((size_t)(kb * 48 + 16 * g + cf) * 64 + lane) * 8;
        bwi[g] = *(const s8*)&wihP[bo];
        bwh[g] = *(const s8*)&whhPh[bo];
        bwl[g] = *(const s8*)&whhPl[bo];
      }
      int axb = l15 * 256 + (((kb * 4 + asub) ^ (l15 & 7)) << 3);
      s8 axh = *(const s8*)&aXp[axb];
      int ab = ((kb * 4 + asub) * 16 + l15) * 8;
      s8 ahh = *(const s8*)&aHh[ab];
      s8 ahl = *(const s8*)&aHl[ab];
      #pragma unroll
      for (int g = 0; g < 3; ++g) {
        gi5[g] = MFMA16(axh, bwi[g], gi5[g]);
        gh5[g] = MFMA16(ahh, bwh[g], gh5[g]);
        gh5[g] = MFMA16(ahl, bwh[g], gh5[g]);
        gh5[g] = MFMA16(ahh, bwl[g], gh5[g]);
      }
    }
    const int col = 16 * cf + l15;
    const float bi0 = bih[col], bi1 = bih[256 + col], bi2 = bih[512 + col];
    const float bh0 = bhh[col], bh1 = bhh[256 + col], bh2 = bhh[512 + col];
    float cm = -1e30f;
    #pragma unroll
    for (int j = 0; j < 4; ++j) {
      const int row = 4 * asub + j;
      const int valid = row < nvalid;
      float sc = scl[row];
      float ir = gi5[0][j] + bi0;
      float iz = gi5[1][j] + bi1;
      float inn = gi5[2][j] + bi2;
      float g0 = bh0 + sc * gh5[0][j];
      float g1 = bh1 + sc * gh5[1][j];
      float g2 = bh2 + sc * gh5[2][j];
      int hix = ((col >> 3) * 16 + row) * 8 + (col & 7);
      float hp = sc * (bf2f(aHh[hix]) + bf2f(aHl[hix]));
      float r = sigmoidf_(ir + g0);
      float z = sigmoidf_(iz + g1);
      float n = tanhf_(inn + r * g2);
      float h = (1.f - z) * n + z * hp;
      u16 hi = f2bf(h);
      u16 lo = f2bf(h - bf2f(hi));
      if (outMode == 1 && j == 3 && valid) {
        int ho = ((col >> 3) * 16 + asub) * 8 + (col & 7);
        outHh[ho] = hi; outHl[ho] = lo;
      } else if (outMode == 2 && valid) {
        outHh[hix] = hi; outHl[hix] = lo;
      } else if (outMode == 3 && j == 3 && valid) {
        gHi[(size_t)(gBase + asub) * 256 + col] = hi;
        gLo[(size_t)(gBase + asub) * 256 + col] = lo;
      }
      if (mode == 2) {
        if (valid)
          atomicMax(outI + (size_t)(batchBase + row) * 256 + col, __float_as_int(h));
      } else if (valid) {
        cm = fmaxf(cm, h);
      }
    }
    if (mode == 0) {
      cm = fmaxf(cm, __shfl_xor(cm, 16));
      cm = fmaxf(cm, __shfl_xor(cm, 32));
      if (asub == 0)
        atomicMax(outI + (size_t)batchBase * 256 + col, __float_as_int(cm));
    }
  }
}

// ---- levelAB: fused L6(64r) + L5(16r). 512 blocks, 2 blocks/CU (LDS). ----
__global__ __launch_bounds__(512, 2)
void levelAB_kernel(const int* __restrict__ t6, const int* __restrict__ t5,
                    const float* __restrict__ emb,
                    const u16* __restrict__ wihP, const u16* __restrict__ whhPh,
                    const u16* __restrict__ whhPl, const u16* __restrict__ swPh,
                    const float* __restrict__ bih, const float* __restrict__ bhh,
                    const float* __restrict__ sb, const float* __restrict__ cw,
                    const float* __restrict__ u0p,
                    u16* __restrict__ Hs5Hi, u16* __restrict__ Hs5Lo,
                    int* __restrict__ outI) {
  __shared__ u16 aX6[16384];   // [64][256], chunk-swizzled
  __shared__ u16 aX5[4096];    // [16][256]
  __shared__ u16 aHh[4096], aHl[4096];  // h6 compact, 16-row transposed
  __shared__ float pm[8][32];
  __shared__ float scl[32];

  const int t = threadIdx.x;
  const int rb = blockIdx.x;   // 0..511
  const int lane = t & 63, w = t >> 6;
  const int asub = lane >> 4, l15 = lane & 15;
  const float LN3 = 1.0986122886681098f;
  const int batch = rb >> 4;

  {
    #pragma unroll
    for (int rr = 0; rr < 8; ++rr) {
      int r = 8 * w + rr;
      stage_row(emb, t6[4 * (64 * rb + r) + 3], aX6, r, lane);
    }
    #pragma unroll
    for (int rr = 0; rr < 2; ++rr) {
      int r = 2 * w + rr;
      stage_row(emb, t5[4 * (16 * rb + r) + 3], aX5, r, lane);
    }
  }
  __syncthreads();

  // ---- L6: 2 passes over jc (same per-pass shape as r14) ----
  #pragma unroll 1
  for (int jc = 0; jc < 2; ++jc) {
    const int cfx = 2 * w + jc;
    f4 gi[3][4];
    #pragma unroll
    for (int g = 0; g < 3; ++g)
      #pragma unroll
      for (int mf = 0; mf < 4; ++mf) gi[g][mf] = (f4){0.f, 0.f, 0.f, 0.f};
    s8 bw[2][3];
    auto LB = [&](int kb, int pb) {
      #pragma unroll
      for (int g = 0; g < 3; ++g)
        bw[pb][g] = *(const s8*)&wihP[((size_t)(kb * 48 + 16 * g + cfx) * 64 + lane) * 8];
    };
    LB(0, 0);
    #pragma unroll
    for (int kb = 0; kb < 8; ++kb) {
      const int pb = kb & 1;
      if (kb < 7) LB(kb + 1, pb ^ 1);
      s8 axh[4];
      #pragma unroll
      for (int mf = 0; mf < 4; ++mf) {
        int ab = (16 * mf + l15) * 256 + (((kb * 4 + asub) ^ (l15 & 7)) << 3);
        axh[mf] = *(const s8*)&aX6[ab];
      }
      #pragma unroll
      for (int g = 0; g < 3; ++g)
        #pragma unroll
        for (int mf = 0; mf < 4; ++mf)
          gi[g][mf] = MFMA16(axh[mf], bw[pb][g], gi[g][mf]);
    }
    const int col = 16 * cfx + l15;
    const float bi0 = bih[col], bi1 = bih[256 + col], bi2 = bih[512 + col];
    const float bh0 = bhh[col], bh1 = bhh[256 + col], bh2 = bhh[512 + col];
    float cm = -1e30f;
    #pragma unroll
    for (int mf = 0; mf < 4; ++mf) {
      #pragma unroll
      for (int j = 0; j < 4; ++j) {
        float r = sigmoidf_(gi[0][mf][j] + bi0 + bh0);
        float z = sigmoidf_(gi[1][mf][j] + bi1 + bh1);
        float n = tanhf_(gi[2][mf][j] + bi2 + r * bh2);
        float h = (1.f - z) * n;
        if (j == 3) {
          int ci = 4 * mf + asub;   // compact row 0..15
          u16 hi = f2bf(h);
          u16 lo = f2bf(h - bf2f(hi));
          int hidx = ((col >> 3) * 16 + ci) * 8 + (col & 7);
          aHh[hidx] = hi;
          aHl[hidx] = lo;
        }
        cm = fmaxf(cm, h);
      }
    }
    cm = fmaxf(cm, __shfl_xor(cm, 16));
    cm = fmaxf(cm, __shfl_xor(cm, 32));
    if (asub == 0)
      atomicMax(outI + (size_t)batch * 256 + col, __float_as_int(cm));
  }
  __syncthreads();

  // ---- L5: level16 with global compact write (rows 4rb..4rb+3 of Hs5) ----
  level16(aX5, aHh, aHl, wihP, whhPh, whhPl, swPh, bih, bhh, sb, cw, u0p[0],
          LN3, 16, nullptr, nullptr, 3, Hs5Hi, Hs5Lo, 4 * rb,
          outI, 0, batch, pm, scl, t);
}

// ---- levelB: L4. col-split x2 (r14/r17 verbatim) ----
__global__ __launch_bounds__(512, 2)
void levelB_kernel(const int* __restrict__ tokens, const float* __restrict__ emb,
                   const u16* __restrict__ wihP, const u16* __restrict__ whhPh,
                   const u16* __restrict__ whhPl, const u16* __restrict__ swPh,
                   const float* __restrict__ bih, const float* __restrict__ bhh,
                   const float* __restrict__ sb, const float* __restrict__ cw,
                   const float* __restrict__ u0p,
                   const u16* __restrict__ HpHi, const u16* __restrict__ HpLo,
                   u16* __restrict__ HoutHi, u16* __restrict__ HoutLo,
                   int* __restrict__ outI, float logSm1, int bshift) {
  __shared__ u16 aX[8192];
  __shared__ u16 aH[2][8192];
  __shared__ float pm[8][32];
  __shared__ float scl[32];

  const int t = threadIdx.x;
  const int rb = blockIdx.x >> 1, cb = blockIdx.x & 1;
  const int i0 = rb * 32;
  const int lane = t & 63, w = t >> 6;

  {
    int row = lane & 31;
    const u16* sh = HpHi + ((size_t)(i0 + row) << 8);
    const u16* sl = HpLo + ((size_t)(i0 + row) << 8);
    #pragma unroll
    for (int c = 0; c < 2; ++c) {
      int cg = w * 4 + c * 2 + (lane >> 5);
      int lb = w * 1024 + c * 512;
      gload_lds16(sh + (cg << 3), &aH[0][lb]);
      gload_lds16(sl + (cg << 3), &aH[1][lb]);
    }
  }
  {
    #pragma unroll
    for (int rr = 0; rr < 4; ++rr) {
      int r = 4 * w + rr;
      int tok = tokens[4 * (i0 + r) + 3];
      stage_row(emb, tok, aX, r, lane);
    }
  }
  __syncthreads();

  const int asub = lane >> 4, l15 = lane & 15;
  const int cfg = 8 * cb + w;

  f4 gi[3][2], gh[3][2], sa[2][2];
  #pragma unroll
  for (int g = 0; g < 3; ++g)
    #pragma unroll
    for (int mf = 0; mf < 2; ++mf) {
      gi[g][mf] = (f4){0.f, 0.f, 0.f, 0.f};
      gh[g][mf] = (f4){0.f, 0.f, 0.f, 0.f};
    }
  #pragma unroll
  for (int jc = 0; jc < 2; ++jc)
    #pragma unroll
    for (int mf = 0; mf < 2; ++mf) sa[jc][mf] = (f4){0.f, 0.f, 0.f, 0.f};

  #pragma unroll
  for (int kb = 0; kb < 8; ++kb) {
    s8 bwi[3], bwh[3], bwl[3], bsw[2];
    #pragma unroll
    for (int g = 0; g < 3; ++g) {
      size_t bo = ((size_t)(kb * 48 + 16 * g + cfg) * 64 + lane) * 8;
      bwi[g] = *(const s8*)&wihP[bo];
      bwh[g] = *(const s8*)&whhPh[bo];
      bwl[g] = *(const s8*)&whhPl[bo];
    }
    #pragma unroll
    for (int jc = 0; jc < 2; ++jc) {
      size_t so = ((size_t)(kb * 16 + 2 * w + jc) * 64 + lane) * 8;
      bsw[jc] = *(const s8*)&swPh[so];
    }
    s8 axh[2], ahh[2], ahl[2];
    #pragma unroll
    for (int mf = 0; mf < 2; ++mf) {
      int axb = (16 * mf + l15) * 256 + (((kb * 4 + asub) ^ (l15 & 7)) << 3);
      axh[mf] = *(const s8*)&aX[axb];
      int abase = ((kb * 4 + asub) * 32 + 16 * mf + l15) * 8;
      ahh[mf] = *(const s8*)&aH[0][abase];
      ahl[mf] = *(const s8*)&aH[1][abase];
    }
    #pragma unroll
    for (int g = 0; g < 3; ++g) {
      gi[g][0] = MFMA16(axh[0], bwi[g], gi[g][0]);
      gi[g][1] = MFMA16(axh[1], bwi[g], gi[g][1]);
      gh[g][0] = MFMA16(ahh[0], bwh[g], gh[g][0]);
      gh[g][1] = MFMA16(ahh[1], bwh[g], gh[g][1]);
      gh[g][0] = MFMA16(ahl[0], bwh[g], gh[g][0]);
      gh[g][1] = MFMA16(ahl[1], bwh[g], gh[g][1]);
      gh[g][0] = MFMA16(ahh[0], bwl[g], gh[g][0]);
      gh[g][1] = MFMA16(ahh[1], bwl[g], gh[g][1]);
    }
    #pragma unroll
    for (int jc = 0; jc < 2; ++jc) {
      sa[jc][0] = MFMA16(ahh[0], bsw[jc], sa[jc][0]);
      sa[jc][1] = MFMA16(ahh[1], bsw[jc], sa[jc][1]);
      sa[jc][0] = MFMA16(ahl[0], bsw[jc], sa[jc][0]);
      sa[jc][1] = MFMA16(ahl[1], bsw[jc], sa[jc][1]);
    }
  }

  {
    float part[2][4] = {{0.f, 0.f, 0.f, 0.f}, {0.f, 0.f, 0.f, 0.f}};
    #pragma unroll
    for (int jc = 0; jc < 2; ++jc) {
      int k = 16 * (2 * w + jc) + l15;
      float sbk = sb[k], cwk = cw[k];
      #pragma unroll
      for (int mf = 0; mf < 2; ++mf)
        #pragma unroll
        for (int j = 0; j < 4; ++j) part[mf][j] += tanhf_(sa[jc][mf][j] + sbk) * cwk;
    }
    #pragma unroll
    for (int mf = 0; mf < 2; ++mf)
      #pragma unroll
      for (int j = 0; j < 4; ++j) {
        part[mf][j] += __shfl_xor(part[mf][j], 1);
        part[mf][j] += __shfl_xor(part[mf][j], 2);
        part[mf][j] += __shfl_xor(part[mf][j], 4);
        part[mf][j] += __shfl_xor(part[mf][j], 8);
      }
    if (l15 == 0) {
      #pragma unroll
      for (int mf = 0; mf < 2; ++mf)
        #pragma unroll
        for (int j = 0; j < 4; ++j) pm[w][16 * mf + 4 * asub + j] = part[mf][j];
    }
    __syncthreads();
    if (t < 32) {
      float v = 0.f;
      #pragma unroll
      for (int q = 0; q < 8; ++q) v += pm[q][t];
      scl[t] = sigmoidf_(tanhf_(v) - u0p[0] - logSm1);
    }
    __syncthreads();
  }

  {
    const int col = 16 * cfg + l15;
    const float bi0 = bih[col], bi1 = bih[256 + col], bi2 = bih[512 + col];
    const float bh0 = bhh[col], bh1 = bhh[256 + col], bh2 = bhh[512 + col];
    float cmax = -1e30f;
    #pragma unroll
    for (int mf = 0; mf < 2; ++mf) {
      const int r0 = 16 * mf + 4 * asub;
      #pragma unroll
      for (int j = 0; j < 4; ++j) {
        const int row = r0 + j;
        const int i = i0 + row;
        float sc = scl[row];
        float ir = gi[0][mf][j] + bi0;
        float iz = gi[1][mf][j] + bi1;
        float inn = gi[2][mf][j] + bi2;
        float g0 = bh0 + sc * gh[0][mf][j];
        float g1 = bh1 + sc * gh[1][mf][j];
        float g2 = bh2 + sc * gh[2][mf][j];
        int hidx = ((col >> 3) * 32 + row) * 8 + (col & 7);
        float hp = sc * (bf2f(aH[0][hidx]) + bf2f(aH[1][hidx]));
        float r = sigmoidf_(ir + g0);
        float z = sigmoidf_(iz + g1);
        float n = tanhf_(inn + r * g2);
        float h = (1.f - z) * n + z * hp;
        if ((i & 3) == 3) {
          u16 hi = f2bf(h);
          u16 lo = f2bf(h - bf2f(hi));
          HoutHi[(size_t)(i >> 2) * 256 + col] = hi;
          HoutLo[(size_t)(i >> 2) * 256 + col] = lo;
        }
        cmax = fmaxf(cmax, h);
      }
    }
    cmax = fmaxf(cmax, __shfl_xor(cmax, 16));
    cmax = fmaxf(cmax, __shfl_xor(cmax, 32));
    if (asub == 0)
      atomicMax(outI + (size_t)(i0 >> bshift) * 256 + col, __float_as_int(cmax));
  }
}

// ---- tailF2: L3(16r) -> L2(4r) -> L1(1r) -> L0(1r) per block, 32 blocks ----
__global__ __launch_bounds__(512, 2)
void tailF2_kernel(const int* __restrict__ t3, const int* __restrict__ t2,
                   const int* __restrict__ t1, const int* __restrict__ t0,
                   const float* __restrict__ emb,
                   const u16* __restrict__ wihP, const u16* __restrict__ whhPh,
                   const u16* __restrict__ whhPl, const u16* __restrict__ swPh,
                   const float* __restrict__ bih, const float* __restrict__ bhh,
                   const float* __restrict__ sb, const float* __restrict__ cw,
                   const float* __restrict__ u0p,
                   const u16* __restrict__ Hs4Hi, const u16* __restrict__ Hs4Lo,
                   int* __restrict__ outI) {
  __shared__ u16 aX3[4096], aH3h[4096], aH3l[4096];
  __shared__ u16 aX2[4096], aH2h[4096], aH2l[4096];
  __shared__ u16 aX1[4096], aH1h[4096], aH1l[4096];
  __shared__ u16 aX0[4096], aH0h[4096], aH0l[4096];
  __shared__ float pm[8][32];
  __shared__ float scl[32];

  const int t = threadIdx.x, b = blockIdx.x;
  const int lane = t & 63, w = t >> 6;
  const float LN3 = 1.0986122886681098f;
  const float LN31 = 3.4339872044851463f;
  const float u0v = u0p[0];

  {
    int row = t & 15, kg = t >> 4;
    uint4 vh = *(const uint4*)&Hs4Hi[(size_t)(16 * b + row) * 256 + kg * 8];
    uint4 vl = *(const uint4*)&Hs4Lo[(size_t)(16 * b + row) * 256 + kg * 8];
    *(uint4*)&aH3h[(kg * 16 + row) * 8] = vh;
    *(uint4*)&aH3l[(kg * 16 + row) * 8] = vl;
    stage_row(emb, t3[4 * (16 * b + w) + 3], aX3, w, lane);
    stage_row(emb, t3[4 * (16 * b + w + 8) + 3], aX3, w + 8, lane);
    if (w < 4) stage_row(emb, t2[4 * (4 * b + w) + 3], aX2, w, lane);
    if (w == 4) stage_row(emb, t1[4 * b + 3], aX1, 0, lane);
    if (w == 5) stage_row(emb, t0[b], aX0, 0, lane);
  }
  __syncthreads();

  level16(aX3, aH3h, aH3l, wihP, whhPh, whhPl, swPh, bih, bhh, sb, cw, u0v,
          LN3, 16, aH2h, aH2l, 1, nullptr, nullptr, 0, outI, 0, b, pm, scl, t);
  __syncthreads();
  level16(aX2, aH2h, aH2l, wihP, whhPh, whhPl, swPh, bih, bhh, sb, cw, u0v,
          LN3, 4, aH1h, aH1l, 1, nullptr, nullptr, 0, outI, 0, b, pm, scl, t);
  __syncthreads();
  level16(aX1, aH1h, aH1l, wihP, whhPh, whhPl, swPh, bih, bhh, sb, cw, u0v,
          LN3, 1, aH0h, aH0l, 2, nullptr, nullptr, 0, outI, 2, b, pm, scl, t);
  __syncthreads();
  level16(aX0, aH0h, aH0l, wihP, whhPh, whhPl, swPh, bih, bhh, sb, cw, u0v,
          LN31, 1, nullptr, nullptr, 0, nullptr, nullptr, 0, outI, 2, b, pm, scl, t);
}

extern "C" void kernel_launch(void* const* d_in, const int* in_sizes, int n_in,
                              void* d_out, int out_size, void* d_ws, size_t ws_size,
                              hipStream_t stream) {
  const int*   tokens = (const int*)d_in[0];
  const float* emb    = (const float*)d_in[1];
  const float* wih    = (const float*)d_in[2];
  const float* whh    = (const float*)d_in[3];
  const float* bih    = (const float*)d_in[4];
  const float* bhh    = (const float*)d_in[5];
  const float* sw     = (const float*)d_in[6];
  const float* sb     = (const float*)d_in[7];
  const float* cw     = (const float*)d_in[8];

  char* ws = (char*)d_ws;
  u16* wihP  = (u16*)(ws + 0);
  u16* whhPh = (u16*)(ws + 393216);
  u16* whhPl = (u16*)(ws + 786432);
  u16* swPh  = (u16*)(ws + 1179648);
  float* u0p = (float*)(ws + 1310720);
  u16* Hs5Hi = (u16*)(ws + 9961472);
  u16* Hs5Lo = (u16*)(ws + 11010048);
  u16* Hs4Hi = (u16*)(ws + 12058624);
  u16* Hs4Lo = (u16*)(ws + 12320768);

  int* outI = (int*)d_out;
  prep_pack<<<321, 256, 0, stream>>>(wih, whh, sw, sb, cw,
                                     wihP, whhPh, whhPl, swPh, u0p, outI);

  const float LN3 = 1.0986122886681098f;

  // L6 + L5 fused, 512 blocks (2 blocks/CU via 58KB LDS)
  levelAB_kernel<<<512, 512, 0, stream>>>(
      tokens + 43680, tokens + 10912, emb, wihP, whhPh, whhPl, swPh,
      bih, bhh, sb, cw, u0p, Hs5Hi, Hs5Lo, outI);
  // L4
  levelB_kernel<<<128, 512, 0, stream>>>(
      tokens + 2720, emb, wihP, whhPh, whhPl, swPh, bih, bhh, sb, cw, u0p,
      Hs5Hi, Hs5Lo, Hs4Hi, Hs4Lo, outI, LN3, 6);
  // L3 -> L2 -> L1 -> L0 fused
  tailF2_kernel<<<32, 512, 0, stream>>>(
      tokens + 672, tokens + 160, tokens + 32, tokens, emb,
      wihP, whhPh, whhPl, swPh, bih, bhh, sb, cw, u0p, Hs4Hi, Hs4Lo, outI);
}

// Round 20
// 119.082 us; speedup vs baseline: 1.5927x; 1.0723x over previous
//
#include <hip/hip_runtime.h>
#include <hip/hip_bf16.h>
#include <math.h>

// BatchTreeEncoder: BS=32, A=4, D=6, H=E=256, V=50000
// Round 20 (final): lock in the measured optimum = round-14 configuration
// (119.9us). All r15-r19 structural variants tied or regressed.
//  - levelAB (256 blocks): fused L6(128r)+L5(32r); 4-pass L6, 4-small-pass
//    L5 gates; spill-free (104 VGPR); wave-per-row coalesced emb gather;
//    fast exp2 transcendentals; shfl-reduced atomicMax epilogue.
//  - levelB (128 blocks): L4 col-split x2.
//  - tail_kernel x4: L3(64)/L2(16)/L1(4)/L0(4) with register-dbuf B loads.
// Split-precision MFMA: gi = x_hi@Wih_hi; gh = (h_hi+h_lo)@Whh_hi +
// h_hi@Whh_lo; hsw 2-term. Compact rows (j%4==3) only; per-row attention
// scale (diagonal identity algebra from round 0).

typedef unsigned short u16;
typedef unsigned int u32;
typedef __attribute__((ext_vector_type(8))) short s8;
typedef __attribute__((ext_vector_type(4))) float f4;
#define MFMA16(a, b, c) __builtin_amdgcn_mfma_f32_16x16x32_bf16(a, b, c, 0, 0, 0)

__device__ __forceinline__ u16 f2bf(float f) {
  u32 x = __float_as_uint(f);
  return (u16)((x + 0x7fffu + ((x >> 16) & 1u)) >> 16);
}
__device__ __forceinline__ float bf2f(u16 u) { return __uint_as_float(((u32)u) << 16); }
__device__ __forceinline__ float sigmoidf_(float x) {
  return __builtin_amdgcn_rcpf(1.f + __builtin_amdgcn_exp2f(-1.4426950408889634f * x));
}
__device__ __forceinline__ float tanhf_(float x) {
  x = fminf(fmaxf(x, -15.f), 15.f);
  float t = __builtin_amdgcn_exp2f(-2.8853900817779268f * x);
  return 1.f - 2.f * t * __builtin_amdgcn_rcpf(1.f + t);
}
__device__ __forceinline__ void gload_lds16(const void* g, void* l) {
  typedef const __attribute__((address_space(1))) unsigned int* gp_t;
  typedef __attribute__((address_space(3))) unsigned int* lp_t;
  __builtin_amdgcn_global_load_lds((gp_t)g, (lp_t)l, 16, 0, 0);
}
__device__ __forceinline__ void stage_row(const float* __restrict__ emb, int tok,
                                          u16* aX, int r, int lane) {
  float4 v = ((const float4*)(emb + (size_t)tok * 256))[lane];
  uint2 val = {(u32)f2bf(v.x) | ((u32)f2bf(v.y) << 16),
               (u32)f2bf(v.z) | ((u32)f2bf(v.w) << 16)};
  *(uint2*)&aX[r * 256 + ((((lane >> 1)) ^ (r & 7)) << 3) + (lane & 1) * 4] = val;
}

// ---- prep: weight pack (0..319), u0 + out-zero (320) ----
__global__ void prep_pack(const float* __restrict__ wih, const float* __restrict__ whh,
                          const float* __restrict__ sw, const float* __restrict__ sb,
                          const float* __restrict__ cw,
                          u16* __restrict__ wihP, u16* __restrict__ whhPh,
                          u16* __restrict__ whhPl, u16* __restrict__ swPh,
                          float* __restrict__ u0p, int* __restrict__ outI) {
  int b = blockIdx.x, t = threadIdx.x;
  if (b == 320) {
    #pragma unroll
    for (int k = 0; k < 32; ++k) outI[k * 256 + t] = 0;
    if (t < 64) {
      float s = 0.f;
      #pragma unroll
      for (int q = 0; q < 4; ++q) { int k = t + 64 * q; s += tanhf(sb[k]) * cw[k]; }
      #pragma unroll
      for (int off = 32; off >= 1; off >>= 1) s += __shfl_xor(s, off);
      if (t == 0) u0p[0] = tanhf(s);
    }
    return;
  }
  int g = b * 256 + t;   // 0..81919
  const float* src;
  u16* dst;
  int idx, NF, lomode, trans;
  if (g < 24576)      { idx = g;         src = wih; dst = wihP;  NF = 48; lomode = 0; trans = 1; }
  else if (g < 49152) { idx = g - 24576; src = whh; dst = whhPh; NF = 48; lomode = 0; trans = 1; }
  else if (g < 73728) { idx = g - 49152; src = whh; dst = whhPl; NF = 48; lomode = 1; trans = 1; }
  else                { idx = g - 73728; src = sw;  dst = swPh;  NF = 16; lomode = 0; trans = 0; }
  int lane = idx & 63;
  int t2 = idx >> 6;
  int nf = t2 % NF, kb = t2 / NF;
  int n = nf * 16 + (lane & 15);
  int k0 = kb * 32 + (lane >> 4) * 8;
  float v[8];
  if (trans) {
    const float4* p = (const float4*)(src + (size_t)n * 256 + k0);
    float4 a = p[0], b2 = p[1];
    v[0] = a.x; v[1] = a.y; v[2] = a.z; v[3] = a.w;
    v[4] = b2.x; v[5] = b2.y; v[6] = b2.z; v[7] = b2.w;
  } else {
    #pragma unroll
    for (int j = 0; j < 8; ++j) v[j] = src[(size_t)(k0 + j) * 256 + n];
  }
  u16 o[8];
  #pragma unroll
  for (int j = 0; j < 8; ++j) {
    u16 hi = f2bf(v[j]);
    o[j] = lomode ? f2bf(v[j] - bf2f(hi)) : hi;
  }
  u32* d = (u32*)(dst + (size_t)idx * 8);
  #pragma unroll
  for (int j = 0; j < 4; ++j) d[j] = (u32)o[2 * j] | ((u32)o[2 * j + 1] << 16);
}

// ---- levelAB: fused L6 + L5. 256 blocks. Small passes, <=128 VGPR. ----
__global__ __launch_bounds__(512, 2)
void levelAB_kernel(const int* __restrict__ t6, const int* __restrict__ t5,
                    const float* __restrict__ emb,
                    const u16* __restrict__ wihP, const u16* __restrict__ whhPh,
                    const u16* __restrict__ whhPl, const u16* __restrict__ swPh,
                    const float* __restrict__ bih, const float* __restrict__ bhh,
                    const float* __restrict__ sb, const float* __restrict__ cw,
                    const float* __restrict__ u0p,
                    u16* __restrict__ Hs5Hi, u16* __restrict__ Hs5Lo,
                    int* __restrict__ outI) {
  __shared__ u16 aX6[32768];
  __shared__ u16 aX5[8192];
  __shared__ u16 aH[2][8192];
  __shared__ float pm[8][32];
  __shared__ float scl[32];

  const int t = threadIdx.x;
  const int rb = blockIdx.x;
  const int lane = t & 63, w = t >> 6;
  const int asub = lane >> 4, l15 = lane & 15;
  const float LN3 = 1.0986122886681098f;
  const int batch = rb >> 3;

  {
    #pragma unroll
    for (int rr = 0; rr < 16; ++rr) {
      int r = 16 * w + rr;
      stage_row(emb, t6[4 * (128 * rb + r) + 3], aX6, r, lane);
    }
    #pragma unroll
    for (int rr = 0; rr < 4; ++rr) {
      int r = 4 * w + rr;
      stage_row(emb, t5[4 * (32 * rb + r) + 3], aX5, r, lane);
    }
  }
  __syncthreads();

  // ---- L6: 4 small passes over (sp = row-half, jc = col-frag) ----
  #pragma unroll 1
  for (int pass = 0; pass < 4; ++pass) {
    const int sp = pass >> 1, jc = pass & 1;
    const int cfx = 2 * w + jc;
    f4 gi[3][4];
    #pragma unroll
    for (int g = 0; g < 3; ++g)
      #pragma unroll
      for (int mf = 0; mf < 4; ++mf) gi[g][mf] = (f4){0.f, 0.f, 0.f, 0.f};
    s8 bw[2][3];
    auto LB = [&](int kb, int pb) {
      #pragma unroll
      for (int g = 0; g < 3; ++g)
        bw[pb][g] = *(const s8*)&wihP[((size_t)(kb * 48 + 16 * g + cfx) * 64 + lane) * 8];
    };
    LB(0, 0);
    #pragma unroll
    for (int kb = 0; kb < 8; ++kb) {
      const int pb = kb & 1;
      if (kb < 7) LB(kb + 1, pb ^ 1);
      s8 axh[4];
      #pragma unroll
      for (int mf = 0; mf < 4; ++mf) {
        int ab = (64 * sp + 16 * mf + l15) * 256 + (((kb * 4 + asub) ^ (l15 & 7)) << 3);
        axh[mf] = *(const s8*)&aX6[ab];
      }
      #pragma unroll
      for (int g = 0; g < 3; ++g)
        #pragma unroll
        for (int mf = 0; mf < 4; ++mf)
          gi[g][mf] = MFMA16(axh[mf], bw[pb][g], gi[g][mf]);
    }
    const int col = 16 * cfx + l15;
    const float bi0 = bih[col], bi1 = bih[256 + col], bi2 = bih[512 + col];
    const float bh0 = bhh[col], bh1 = bhh[256 + col], bh2 = bhh[512 + col];
    float cm = -1e30f;
    #pragma unroll
    for (int mf = 0; mf < 4; ++mf) {
      #pragma unroll
      for (int j = 0; j < 4; ++j) {
        float r = sigmoidf_(gi[0][mf][j] + bi0 + bh0);
        float z = sigmoidf_(gi[1][mf][j] + bi1 + bh1);
        float n = tanhf_(gi[2][mf][j] + bi2 + r * bh2);
        float h = (1.f - z) * n;
        if (j == 3) {
          int ci = 16 * sp + 4 * mf + asub;
          u16 hi = f2bf(h);
          u16 lo = f2bf(h - bf2f(hi));
          int hidx = ((col >> 3) * 32 + ci) * 8 + (col & 7);
          aH[0][hidx] = hi;
          aH[1][hidx] = lo;
        }
        cm = fmaxf(cm, h);
      }
    }
    cm = fmaxf(cm, __shfl_xor(cm, 16));
    cm = fmaxf(cm, __shfl_xor(cm, 32));
    if (asub == 0)
      atomicMax(outI + (size_t)batch * 256 + col, __float_as_int(cm));
  }
  __syncthreads();

  // ---- L5: sa (32-row) ----
  f4 sa[2][2];
  #pragma unroll
  for (int jc = 0; jc < 2; ++jc)
    #pragma unroll
    for (int mf = 0; mf < 2; ++mf) sa[jc][mf] = (f4){0.f, 0.f, 0.f, 0.f};
  {
    s8 bsw[2][2];
    auto LSW = [&](int kb, int pb) {
      #pragma unroll
      for (int jc = 0; jc < 2; ++jc)
        bsw[pb][jc] = *(const s8*)&swPh[((size_t)(kb * 16 + 2 * w + jc) * 64 + lane) * 8];
    };
    LSW(0, 0);
    #pragma unroll
    for (int kb = 0; kb < 8; ++kb) {
      const int pb = kb & 1;
      if (kb < 7) LSW(kb + 1, pb ^ 1);
      s8 ahh[2], ahl[2];
      #pragma unroll
      for (int mf = 0; mf < 2; ++mf) {
        int ab = ((kb * 4 + asub) * 32 + 16 * mf + l15) * 8;
        ahh[mf] = *(const s8*)&aH[0][ab];
        ahl[mf] = *(const s8*)&aH[1][ab];
      }
      #pragma unroll
      for (int jc = 0; jc < 2; ++jc) {
        sa[jc][0] = MFMA16(ahh[0], bsw[pb][jc], sa[jc][0]);
        sa[jc][1] = MFMA16(ahh[1], bsw[pb][jc], sa[jc][1]);
        sa[jc][0] = MFMA16(ahl[0], bsw[pb][jc], sa[jc][0]);
        sa[jc][1] = MFMA16(ahl[1], bsw[pb][jc], sa[jc][1]);
      }
    }
  }
  {
    float part[2][4] = {{0.f, 0.f, 0.f, 0.f}, {0.f, 0.f, 0.f, 0.f}};
    #pragma unroll
    for (int jc = 0; jc < 2; ++jc) {
      int k = 16 * (2 * w + jc) + l15;
      float sbk = sb[k], cwk = cw[k];
      #pragma unroll
      for (int mf = 0; mf < 2; ++mf)
        #pragma unroll
        for (int j = 0; j < 4; ++j) part[mf][j] += tanhf_(sa[jc][mf][j] + sbk) * cwk;
    }
    #pragma unroll
    for (int mf = 0; mf < 2; ++mf)
      #pragma unroll
      for (int j = 0; j < 4; ++j) {
        part[mf][j] += __shfl_xor(part[mf][j], 1);
        part[mf][j] += __shfl_xor(part[mf][j], 2);
        part[mf][j] += __shfl_xor(part[mf][j], 4);
        part[mf][j] += __shfl_xor(part[mf][j], 8);
      }
    if (l15 == 0) {
      #pragma unroll
      for (int mf = 0; mf < 2; ++mf)
        #pragma unroll
        for (int j = 0; j < 4; ++j) pm[w][16 * mf + 4 * asub + j] = part[mf][j];
    }
    __syncthreads();
    if (t < 32) {
      float v = 0.f;
      #pragma unroll
      for (int q = 0; q < 8; ++q) v += pm[q][t];
      scl[t] = sigmoidf_(tanhf_(v) - u0p[0] - LN3);
    }
    __syncthreads();
  }
  // ---- L5 gates: 4 small passes over (p = col-half, mf = row-frag) ----
  #pragma unroll 1
  for (int pass = 0; pass < 4; ++pass) {
    const int p = pass >> 1, mf = pass & 1;
    const int cf = w + 8 * p;
    f4 gi5[3], gh5[3];
    #pragma unroll
    for (int g = 0; g < 3; ++g) {
      gi5[g] = (f4){0.f, 0.f, 0.f, 0.f};
      gh5[g] = (f4){0.f, 0.f, 0.f, 0.f};
    }
    #pragma unroll
    for (int kb = 0; kb < 8; ++kb) {
      s8 bwi[3], bwh[3], bwl[3];
      #pragma unroll
      for (int g = 0; g < 3; ++g) {
        size_t bo = ((size_t)(kb * 48 + 16 * g + cf) * 64 + lane) * 8;
        bwi[g] = *(const s8*)&wihP[bo];
        bwh[g] = *(const s8*)&whhPh[bo];
        bwl[g] = *(const s8*)&whhPl[bo];
      }
      int axb = (16 * mf + l15) * 256 + (((kb * 4 + asub) ^ (l15 & 7)) << 3);
      s8 axh = *(const s8*)&aX5[axb];
      int ab = ((kb * 4 + asub) * 32 + 16 * mf + l15) * 8;
      s8 ahh = *(const s8*)&aH[0][ab];
      s8 ahl = *(const s8*)&aH[1][ab];
      #pragma unroll
      for (int g = 0; g < 3; ++g) {
        gi5[g] = MFMA16(axh, bwi[g], gi5[g]);
        gh5[g] = MFMA16(ahh, bwh[g], gh5[g]);
        gh5[g] = MFMA16(ahl, bwh[g], gh5[g]);
        gh5[g] = MFMA16(ahh, bwl[g], gh5[g]);
      }
    }
    const int col = 16 * cf + l15;
    const float bi0 = bih[col], bi1 = bih[256 + col], bi2 = bih[512 + col];
    const float bh0 = bhh[col], bh1 = bhh[256 + col], bh2 = bhh[512 + col];
    const int r0 = 16 * mf + 4 * asub;
    float cm = -1e30f;
    #pragma unroll
    for (int j = 0; j < 4; ++j) {
      const int row = r0 + j;
      const int i = 32 * rb + row;
      float sc = scl[row];
      float ir = gi5[0][j] + bi0;
      float iz = gi5[1][j] + bi1;
      float inn = gi5[2][j] + bi2;
      float g0 = bh0 + sc * gh5[0][j];
      float g1 = bh1 + sc * gh5[1][j];
      float g2 = bh2 + sc * gh5[2][j];
      int hidx = ((col >> 3) * 32 + row) * 8 + (col & 7);
      float hp = sc * (bf2f(aH[0][hidx]) + bf2f(aH[1][hidx]));
      float r = sigmoidf_(ir + g0);
      float z = sigmoidf_(iz + g1);
      float n = tanhf_(inn + r * g2);
      float h = (1.f - z) * n + z * hp;
      if (j == 3) {
        u16 hi = f2bf(h);
        u16 lo = f2bf(h - bf2f(hi));
        Hs5Hi[(size_t)(i >> 2) * 256 + col] = hi;
        Hs5Lo[(size_t)(i >> 2) * 256 + col] = lo;
      }
      cm = fmaxf(cm, h);
    }
    cm = fmaxf(cm, __shfl_xor(cm, 16));
    cm = fmaxf(cm, __shfl_xor(cm, 32));
    if (asub == 0)
      atomicMax(outI + (size_t)batch * 256 + col, __float_as_int(cm));
  }
}

// ---- levelB: L4. col-split x2 ----
__global__ __launch_bounds__(512, 2)
void levelB_kernel(const int* __restrict__ tokens, const float* __restrict__ emb,
                   const u16* __restrict__ wihP, const u16* __restrict__ whhPh,
                   const u16* __restrict__ whhPl, const u16* __restrict__ swPh,
                   const float* __restrict__ bih, const float* __restrict__ bhh,
                   const float* __restrict__ sb, const float* __restrict__ cw,
                   const float* __restrict__ u0p,
                   const u16* __restrict__ HpHi, const u16* __restrict__ HpLo,
                   u16* __restrict__ HoutHi, u16* __restrict__ HoutLo,
                   int* __restrict__ outI, float logSm1, int bshift) {
  __shared__ u16 aX[8192];
  __shared__ u16 aH[2][8192];
  __shared__ float pm[8][32];
  __shared__ float scl[32];

  const int t = threadIdx.x;
  const int rb = blockIdx.x >> 1, cb = blockIdx.x & 1;
  const int i0 = rb * 32;
  const int lane = t & 63, w = t >> 6;

  {
    int row = lane & 31;
    const u16* sh = HpHi + ((size_t)(i0 + row) << 8);
    const u16* sl = HpLo + ((size_t)(i0 + row) << 8);
    #pragma unroll
    for (int c = 0; c < 2; ++c) {
      int cg = w * 4 + c * 2 + (lane >> 5);
      int lb = w * 1024 + c * 512;
      gload_lds16(sh + (cg << 3), &aH[0][lb]);
      gload_lds16(sl + (cg << 3), &aH[1][lb]);
    }
  }
  {
    #pragma unroll
    for (int rr = 0; rr < 4; ++rr) {
      int r = 4 * w + rr;
      int tok = tokens[4 * (i0 + r) + 3];
      stage_row(emb, tok, aX, r, lane);
    }
  }
  __syncthreads();

  const int asub = lane >> 4, l15 = lane & 15;
  const int cfg = 8 * cb + w;

  f4 gi[3][2], gh[3][2], sa[2][2];
  #pragma unroll
  for (int g = 0; g < 3; ++g)
    #pragma unroll
    for (int mf = 0; mf < 2; ++mf) {
      gi[g][mf] = (f4){0.f, 0.f, 0.f, 0.f};
      gh[g][mf] = (f4){0.f, 0.f, 0.f, 0.f};
    }
  #pragma unroll
  for (int jc = 0; jc < 2; ++jc)
    #pragma unroll
    for (int mf = 0; mf < 2; ++mf) sa[jc][mf] = (f4){0.f, 0.f, 0.f, 0.f};

  #pragma unroll
  for (int kb = 0; kb < 8; ++kb) {
    s8 bwi[3], bwh[3], bwl[3], bsw[2];
    #pragma unroll
    for (int g = 0; g < 3; ++g) {
      size_t bo = ((size_t)(kb * 48 + 16 * g + cfg) * 64 + lane) * 8;
      bwi[g] = *(const s8*)&wihP[bo];
      bwh[g] = *(const s8*)&whhPh[bo];
      bwl[g] = *(const s8*)&whhPl[bo];
    }
    #pragma unroll
    for (int jc = 0; jc < 2; ++jc) {
      size_t so = ((size_t)(kb * 16 + 2 * w + jc) * 64 + lane) * 8;
      bsw[jc] = *(const s8*)&swPh[so];
    }
    s8 axh[2], ahh[2], ahl[2];
    #pragma unroll
    for (int mf = 0; mf < 2; ++mf) {
      int axb = (16 * mf + l15) * 256 + (((kb * 4 + asub) ^ (l15 & 7)) << 3);
      axh[mf] = *(const s8*)&aX[axb];
      int abase = ((kb * 4 + asub) * 32 + 16 * mf + l15) * 8;
      ahh[mf] = *(const s8*)&aH[0][abase];
      ahl[mf] = *(const s8*)&aH[1][abase];
    }
    #pragma unroll
    for (int g = 0; g < 3; ++g) {
      gi[g][0] = MFMA16(axh[0], bwi[g], gi[g][0]);
      gi[g][1] = MFMA16(axh[1], bwi[g], gi[g][1]);
      gh[g][0] = MFMA16(ahh[0], bwh[g], gh[g][0]);
      gh[g][1] = MFMA16(ahh[1], bwh[g], gh[g][1]);
      gh[g][0] = MFMA16(ahl[0], bwh[g], gh[g][0]);
      gh[g][1] = MFMA16(ahl[1], bwh[g], gh[g][1]);
      gh[g][0] = MFMA16(ahh[0], bwl[g], gh[g][0]);
      gh[g][1] = MFMA16(ahh[1], bwl[g], gh[g][1]);
    }
    #pragma unroll
    for (int jc = 0; jc < 2; ++jc) {
      sa[jc][0] = MFMA16(ahh[0], bsw[jc], sa[jc][0]);
      sa[jc][1] = MFMA16(ahh[1], bsw[jc], sa[jc][1]);
      sa[jc][0] = MFMA16(ahl[0], bsw[jc], sa[jc][0]);
      sa[jc][1] = MFMA16(ahl[1], bsw[jc], sa[jc][1]);
    }
  }

  {
    float part[2][4] = {{0.f, 0.f, 0.f, 0.f}, {0.f, 0.f, 0.f, 0.f}};
    #pragma unroll
    for (int jc = 0; jc < 2; ++jc) {
      int k = 16 * (2 * w + jc) + l15;
      float sbk = sb[k], cwk = cw[k];
      #pragma unroll
      for (int mf = 0; mf < 2; ++mf)
        #pragma unroll
        for (int j = 0; j < 4; ++j) part[mf][j] += tanhf_(sa[jc][mf][j] + sbk) * cwk;
    }
    #pragma unroll
    for (int mf = 0; mf < 2; ++mf)
      #pragma unroll
      for (int j = 0; j < 4; ++j) {
        part[mf][j] += __shfl_xor(part[mf][j], 1);
        part[mf][j] += __shfl_xor(part[mf][j], 2);
        part[mf][j] += __shfl_xor(part[mf][j], 4);
        part[mf][j] += __shfl_xor(part[mf][j], 8);
      }
    if (l15 == 0) {
      #pragma unroll
      for (int mf = 0; mf < 2; ++mf)
        #pragma unroll
        for (int j = 0; j < 4; ++j) pm[w][16 * mf + 4 * asub + j] = part[mf][j];
    }
    __syncthreads();
    if (t < 32) {
      float v = 0.f;
      #pragma unroll
      for (int q = 0; q < 8; ++q) v += pm[q][t];
      scl[t] = sigmoidf_(tanhf_(v) - u0p[0] - logSm1);
    }
    __syncthreads();
  }

  {
    const int col = 16 * cfg + l15;
    const float bi0 = bih[col], bi1 = bih[256 + col], bi2 = bih[512 + col];
    const float bh0 = bhh[col], bh1 = bhh[256 + col], bh2 = bhh[512 + col];
    float cmax = -1e30f;
    #pragma unroll
    for (int mf = 0; mf < 2; ++mf) {
      const int r0 = 16 * mf + 4 * asub;
      #pragma unroll
      for (int j = 0; j < 4; ++j) {
        const int row = r0 + j;
        const int i = i0 + row;
        float sc = scl[row];
        float ir = gi[0][mf][j] + bi0;
        float iz = gi[1][mf][j] + bi1;
        float inn = gi[2][mf][j] + bi2;
        float g0 = bh0 + sc * gh[0][mf][j];
        float g1 = bh1 + sc * gh[1][mf][j];
        float g2 = bh2 + sc * gh[2][mf][j];
        int hidx = ((col >> 3) * 32 + row) * 8 + (col & 7);
        float hp = sc * (bf2f(aH[0][hidx]) + bf2f(aH[1][hidx]));
        float r = sigmoidf_(ir + g0);
        float z = sigmoidf_(iz + g1);
        float n = tanhf_(inn + r * g2);
        float h = (1.f - z) * n + z * hp;
        if ((i & 3) == 3) {
          u16 hi = f2bf(h);
          u16 lo = f2bf(h - bf2f(hi));
          HoutHi[(size_t)(i >> 2) * 256 + col] = hi;
          HoutLo[(size_t)(i >> 2) * 256 + col] = lo;
        }
        cmax = fmaxf(cmax, h);
      }
    }
    cmax = fmaxf(cmax, __shfl_xor(cmax, 16));
    cmax = fmaxf(cmax, __shfl_xor(cmax, 32));
    if (asub == 0)
      atomicMax(outI + (size_t)(i0 >> bshift) * 256 + col, __float_as_int(cmax));
  }
}

// ---- tail kernel (levels 3,2,1,0): col-split x4 + register-dbuf B loads ----
struct Bregs {
  s8 wi[3], wh[3], wl[3], sw[4];
};
__device__ __forceinline__ void loadB(int kb, int cf, int wq, int lane,
                                      const u16* __restrict__ wihP,
                                      const u16* __restrict__ whhPh,
                                      const u16* __restrict__ whhPl,
                                      const u16* __restrict__ swPh, Bregs& r) {
  #pragma unroll
  for (int g = 0; g < 3; ++g) {
    size_t bo = ((size_t)(kb * 48 + 16 * g + cf) * 64 + lane) * 8;
    r.wi[g] = *(const s8*)&wihP[bo];
    r.wh[g] = *(const s8*)&whhPh[bo];
    r.wl[g] = *(const s8*)&whhPl[bo];
  }
  #pragma unroll
  for (int c = 0; c < 4; ++c) {
    size_t so = ((size_t)(kb * 16 + 4 * wq + c) * 64 + lane) * 8;
    r.sw[c] = *(const s8*)&swPh[so];
  }
}

template <bool ROOT>
__global__ __launch_bounds__(512, 2)
void tail_kernel(const int* __restrict__ tokens, const float* __restrict__ emb,
                 const u16* __restrict__ wihP, const u16* __restrict__ whhPh,
                 const u16* __restrict__ whhPl, const u16* __restrict__ swPh,
                 const float* __restrict__ bih, const float* __restrict__ bhh,
                 const float* __restrict__ sb, const float* __restrict__ cw,
                 const float* __restrict__ u0p,
                 const u16* __restrict__ HpHi, const u16* __restrict__ HpLo,
                 u16* __restrict__ HoutHi, u16* __restrict__ HoutLo,
                 int* __restrict__ outI, float logSm1, int bshift, int store_mode) {
  __shared__ u16 aX[8192];
  __shared__ u16 aH[2][8192];
  __shared__ float pm[8][32];
  __shared__ float scl[32];

  const int t = threadIdx.x;
  const int rb = blockIdx.x >> 2, cb = blockIdx.x & 3;
  const int i0 = rb * 32;
  const int lane = t & 63, w = t >> 6;

  {
    int row = lane & 31;
    const u16* sh = HpHi + ((size_t)(i0 + row) << 8);
    const u16* sl = HpLo + ((size_t)(i0 + row) << 8);
    #pragma unroll
    for (int c = 0; c < 2; ++c) {
      int cg = w * 4 + c * 2 + (lane >> 5);
      int lb = w * 1024 + c * 512;
      gload_lds16(sh + (cg << 3), &aH[0][lb]);
      gload_lds16(sl + (cg << 3), &aH[1][lb]);
    }
  }
  {
    #pragma unroll
    for (int rr = 0; rr < 4; ++rr) {
      int r = 4 * w + rr;
      int tok = tokens[ROOT ? (i0 + r) : (4 * (i0 + r) + 3)];
      stage_row(emb, tok, aX, r, lane);
    }
  }
  __syncthreads();

  const int wq = w & 3, mf = w >> 2;
  const int asub = lane >> 4;
  const int l15 = lane & 15;
  const int cf = 4 * cb + wq;

  f4 gi[3], gh[3], sa[4];
  #pragma unroll
  for (int g = 0; g < 3; ++g) { gi[g] = (f4){0.f, 0.f, 0.f, 0.f}; gh[g] = (f4){0.f, 0.f, 0.f, 0.f}; }
  #pragma unroll
  for (int c = 0; c < 4; ++c) sa[c] = (f4){0.f, 0.f, 0.f, 0.f};

  Bregs b0, b1;
  loadB(0, cf, wq, lane, wihP, whhPh, whhPl, swPh, b0);

  #pragma unroll
  for (int kb = 0; kb < 8; ++kb) {
    Bregs& cur = (kb & 1) ? b1 : b0;
    Bregs& nxt = (kb & 1) ? b0 : b1;
    if (kb < 7) loadB(kb + 1, cf, wq, lane, wihP, whhPh, whhPl, swPh, nxt);
    int axb = (16 * mf + l15) * 256 + (((kb * 4 + asub) ^ (l15 & 7)) << 3);
    s8 axh = *(const s8*)&aX[axb];
    int abase = ((kb * 4 + asub) * 32 + 16 * mf + l15) * 8;
    s8 ahh = *(const s8*)&aH[0][abase];
    s8 ahl = *(const s8*)&aH[1][abase];
    #pragma unroll
    for (int g = 0; g < 3; ++g) {
      gi[g] = MFMA16(axh, cur.wi[g], gi[g]);
      gh[g] = MFMA16(ahh, cur.wh[g], gh[g]);
      gh[g] = MFMA16(ahl, cur.wh[g], gh[g]);
      gh[g] = MFMA16(ahh, cur.wl[g], gh[g]);
    }
    #pragma unroll
    for (int c = 0; c < 4; ++c) {
      sa[c] = MFMA16(ahh, cur.sw[c], sa[c]);
      sa[c] = MFMA16(ahl, cur.sw[c], sa[c]);
    }
  }

  {
    float part[4] = {0.f, 0.f, 0.f, 0.f};
    #pragma unroll
    for (int c = 0; c < 4; ++c) {
      int k = 16 * (4 * wq + c) + l15;
      float sbk = sb[k], cwk = cw[k];
      #pragma unroll
      for (int j = 0; j < 4; ++j) part[j] += tanhf_(sa[c][j] + sbk) * cwk;
    }
    #pragma unroll
    for (int j = 0; j < 4; ++j) {
      part[j] += __shfl_xor(part[j], 1);
      part[j] += __shfl_xor(part[j], 2);
      part[j] += __shfl_xor(part[j], 4);
      part[j] += __shfl_xor(part[j], 8);
    }
    if (l15 == 0) {
      #pragma unroll
      for (int j = 0; j < 4; ++j) pm[w][16 * mf + 4 * asub + j] = part[j];
    }
    __syncthreads();
    if (t < 32) {
      int q0 = (t >> 4) * 4;
      float v = pm[q0][t] + pm[q0 + 1][t] + pm[q0 + 2][t] + pm[q0 + 3][t];
      scl[t] = sigmoidf_(tanhf_(v) - u0p[0] - logSm1);
    }
    __syncthreads();
  }

  {
    const int col = 16 * cf + l15;
    const float bi0 = bih[col], bi1 = bih[256 + col], bi2 = bih[512 + col];
    const float bh0 = bhh[col], bh1 = bhh[256 + col], bh2 = bhh[512 + col];
    const int r0 = 16 * mf + 4 * asub;
    float hmax = -1e30f;
    #pragma unroll
    for (int j = 0; j < 4; ++j) {
      const int row = r0 + j;
      const int i = i0 + row;
      float sc = scl[row];
      float ir = gi[0][j] + bi0;
      float iz = gi[1][j] + bi1;
      float inn = gi[2][j] + bi2;
      float g0 = bh0 + sc * gh[0][j];
      float g1 = bh1 + sc * gh[1][j];
      float g2 = bh2 + sc * gh[2][j];
      int hidx = ((col >> 3) * 32 + row) * 8 + (col & 7);
      float hp = sc * (bf2f(aH[0][hidx]) + bf2f(aH[1][hidx]));
      float r = sigmoidf_(ir + g0);
      float z = sigmoidf_(iz + g1);
      float n = tanhf_(inn + r * g2);
      float h = (1.f - z) * n + z * hp;
      if (store_mode == 1) {
        u16 hi = f2bf(h);
        u16 lo = f2bf(h - bf2f(hi));
        HoutHi[(size_t)i * 256 + col] = hi;
        HoutLo[(size_t)i * 256 + col] = lo;
      } else if (store_mode == 2 && ((i & 3) == 3)) {
        u16 hi = f2bf(h);
        u16 lo = f2bf(h - bf2f(hi));
        HoutHi[(size_t)(i >> 2) * 256 + col] = hi;
        HoutLo[(size_t)(i >> 2) * 256 + col] = lo;
      }
      if (bshift >= 2) {
        hmax = (j == 0) ? h : fmaxf(hmax, h);
      } else {
        atomicMax(outI + (size_t)i * 256 + col, __float_as_int(h));
      }
    }
    if (bshift >= 4) {
      hmax = fmaxf(hmax, __shfl_xor(hmax, 16));
      hmax = fmaxf(hmax, __shfl_xor(hmax, 32));
      if (asub == 0)
        atomicMax(outI + (size_t)((i0 + 16 * mf) >> bshift) * 256 + col,
                  __float_as_int(hmax));
    } else if (bshift >= 2) {
      atomicMax(outI + (size_t)((i0 + r0) >> bshift) * 256 + col, __float_as_int(hmax));
    }
  }
}

extern "C" void kernel_launch(void* const* d_in, const int* in_sizes, int n_in,
                              void* d_out, int out_size, void* d_ws, size_t ws_size,
                              hipStream_t stream) {
  const int*   tokens = (const int*)d_in[0];
  const float* emb    = (const float*)d_in[1];
  const float* wih    = (const float*)d_in[2];
  const float* whh    = (const float*)d_in[3];
  const float* bih    = (const float*)d_in[4];
  const float* bhh    = (const float*)d_in[5];
  const float* sw     = (const float*)d_in[6];
  const float* sb     = (const float*)d_in[7];
  const float* cw     = (const float*)d_in[8];

  char* ws = (char*)d_ws;
  u16* wihP  = (u16*)(ws + 0);
  u16* whhPh = (u16*)(ws + 393216);
  u16* whhPl = (u16*)(ws + 786432);
  u16* swPh  = (u16*)(ws + 1179648);
  float* u0p = (float*)(ws + 1310720);
  u16* H1Hi  = (u16*)(ws + 1310976);
  u16* H1Lo  = (u16*)(ws + 1327360);
  u16* Hs5Hi = (u16*)(ws + 9961472);
  u16* Hs5Lo = (u16*)(ws + 11010048);
  u16* Hs4Hi = (u16*)(ws + 12058624);
  u16* Hs4Lo = (u16*)(ws + 12320768);
  u16* Hs3Hi = (u16*)(ws + 12582912);
  u16* Hs3Lo = (u16*)(ws + 12648448);
  u16* Hs2Hi = (u16*)(ws + 12713984);
  u16* Hs2Lo = (u16*)(ws + 12730368);

  int* outI = (int*)d_out;
  prep_pack<<<321, 256, 0, stream>>>(wih, whh, sw, sb, cw,
                                     wihP, whhPh, whhPl, swPh, u0p, outI);

  const float LN3  = 1.0986122886681098f;   // ln(A-1)
  const float LN31 = 3.4339872044851463f;   // ln(BS-1)

  // L6 + L5 fused
  levelAB_kernel<<<256, 512, 0, stream>>>(
      tokens + 43680, tokens + 10912, emb, wihP, whhPh, whhPl, swPh,
      bih, bhh, sb, cw, u0p, Hs5Hi, Hs5Lo, outI);
  // L4 (col-split x2)
  levelB_kernel<<<128, 512, 0, stream>>>(
      tokens + 2720, emb, wihP, whhPh, whhPl, swPh, bih, bhh, sb, cw, u0p,
      Hs5Hi, Hs5Lo, Hs4Hi, Hs4Lo, outI, LN3, 6);
  // L3, L2 (col-split x4)
  tail_kernel<false><<<64, 512, 0, stream>>>(
      tokens + 672, emb, wihP, whhPh, whhPl, swPh, bih, bhh, sb, cw, u0p,
      Hs4Hi, Hs4Lo, Hs3Hi, Hs3Lo, outI, LN3, 4, 2);
  tail_kernel<false><<<16, 512, 0, stream>>>(
      tokens + 160, emb, wihP, whhPh, whhPl, swPh, bih, bhh, sb, cw, u0p,
      Hs3Hi, Hs3Lo, Hs2Hi, Hs2Lo, outI, LN3, 2, 2);
  // L1 (full-plane store for L0), L0 (ROOT)
  tail_kernel<false><<<4, 512, 0, stream>>>(
      tokens + 32, emb, wihP, whhPh, whhPl, swPh, bih, bhh, sb, cw, u0p,
      Hs2Hi, Hs2Lo, H1Hi, H1Lo, outI, LN3, 0, 1);
  tail_kernel<true><<<4, 512, 0, stream>>>(
      tokens + 0, emb, wihP, whhPh, whhPl, swPh, bih, bhh, sb, cw, u0p,
      H1Hi, H1Lo, nullptr, nullptr, outI, LN31, 0, 0);
}